// Round 1
// baseline (513.775 us; speedup 1.0000x reference)
//
#include <hip/hip_runtime.h>
#include <hip/hip_bf16.h>
#include <cfloat>

#define GT 16
#define NCLS 81
#define ROWS 128
#define TPB 256
#define MAXP 8732

__device__ __forceinline__ float smoothl1(float d){
  float a = fabsf(d);
  return a < 1.0f ? 0.5f*a*a : a - 0.5f;
}

// Kernel 1: per-batch GT<->prior assignment + box loss + labels
__global__ __launch_bounds__(TPB) void assign_kernel(
    const float* __restrict__ priors,     // (P,4) xywh
    const float* __restrict__ gt_boxes,   // (B,GT,4) xyxy
    const int*  __restrict__ gt_labels,   // (B,GT)
    const float* __restrict__ box_reg,    // (B,P,4)
    int*   __restrict__ labels_out,       // (B,P)
    float* __restrict__ sl1_sum,          // (B)
    int*   __restrict__ num_pos,          // (B)
    float* __restrict__ ce_pos,           // (B) zero-init here
    int P)
{
  const int b = blockIdx.x;
  const int tid = threadIdx.x;
  const int wave = tid >> 6, lane = tid & 63;

  __shared__ float s_mv[MAXP];
  __shared__ unsigned char s_match[MAXP];
  __shared__ float s_gx0[GT], s_gy0[GT], s_gx1[GT], s_gy1[GT], s_garea[GT];
  __shared__ int s_glab[GT];
  __shared__ float s_redv[4*GT];
  __shared__ int   s_redi[4*GT];
  __shared__ int   s_bp[GT];
  __shared__ float s_rs[4];
  __shared__ int   s_rc[4];

  if (tid == 0) ce_pos[b] = 0.0f;
  if (tid < GT){
    const float4 gb = ((const float4*)gt_boxes)[b*GT + tid];
    s_gx0[tid]=gb.x; s_gy0[tid]=gb.y; s_gx1[tid]=gb.z; s_gy1[tid]=gb.w;
    s_garea[tid] = (gb.z-gb.x)*(gb.w-gb.y);
    s_glab[tid] = gt_labels[b*GT + tid];
  }
  __syncthreads();

  float bestv[GT]; int besti[GT];
  #pragma unroll
  for (int g=0; g<GT; ++g){ bestv[g] = -1.0f; besti[g] = 0x7fffffff; }

  for (int p = tid; p < P; p += TPB){
    const float4 pr = ((const float4*)priors)[p];  // xywh
    const float px0 = pr.x - pr.z*0.5f, py0 = pr.y - pr.w*0.5f;
    const float px1 = pr.x + pr.z*0.5f, py1 = pr.y + pr.w*0.5f;
    const float parea = (px1-px0)*(py1-py0);
    float mv = -1.0f; int mi = 0;
    #pragma unroll
    for (int g=0; g<GT; ++g){
      const float ltx = fmaxf(s_gx0[g], px0), lty = fmaxf(s_gy0[g], py0);
      const float rbx = fminf(s_gx1[g], px1), rby = fminf(s_gy1[g], py1);
      const float w = fmaxf(rbx-ltx, 0.0f), h = fmaxf(rby-lty, 0.0f);
      const float inter = w*h;
      const float iou = inter / (s_garea[g] + parea - inter);
      if (iou > mv){ mv = iou; mi = g; }            // first-max over g
      if (iou > bestv[g]){ bestv[g] = iou; besti[g] = p; } // first-max over p (ascending)
    }
    s_mv[p] = mv;
    s_match[p] = (unsigned char)mi;
  }

  // reduce per-g (val, min idx on tie) across block
  #pragma unroll
  for (int g=0; g<GT; ++g){
    float v = bestv[g]; int i = besti[g];
    for (int off=32; off>0; off>>=1){
      float ov = __shfl_down(v, off);
      int   oi = __shfl_down(i, off);
      if (ov > v || (ov == v && oi < i)){ v = ov; i = oi; }
    }
    if (lane == 0){ s_redv[wave*GT+g] = v; s_redi[wave*GT+g] = i; }
  }
  __syncthreads();
  if (tid < GT){
    float v = s_redv[tid]; int i = s_redi[tid];
    for (int w=1; w<4; ++w){
      float ov = s_redv[w*GT+tid]; int oi = s_redi[w*GT+tid];
      if (ov > v || (ov == v && oi < i)){ v = ov; i = oi; }
    }
    s_bp[tid] = i;
  }
  __syncthreads();
  if (tid == 0){
    for (int g=0; g<GT; ++g){       // sequential: last g wins on duplicates
      int bp = s_bp[g];
      s_mv[bp] = 2.0f;
      s_match[bp] = (unsigned char)g;
    }
  }
  __syncthreads();

  // phase 2: labels + encode + smooth-L1 over positives
  float sl1 = 0.0f; int cnt = 0;
  for (int p = tid; p < P; p += TPB){
    const float mv = s_mv[p];
    const int g = s_match[p];
    int lab = 0;
    if (mv >= 0.5f){
      lab = s_glab[g];
      cnt++;
      const float4 pr = ((const float4*)priors)[p];
      const float bx0 = s_gx0[g], by0 = s_gy0[g], bx1 = s_gx1[g], by1 = s_gy1[g];
      const float ctrx = (bx0+bx1)*0.5f, ctry = (by0+by1)*0.5f;
      const float wx = bx1-bx0, wy = by1-by0;
      const float tx = (ctrx - pr.x) / (0.1f*pr.z);
      const float ty = (ctry - pr.y) / (0.1f*pr.w);
      const float tw = logf(wx/pr.z) / 0.2f;
      const float th = logf(wy/pr.w) / 0.2f;
      const float4 br = ((const float4*)box_reg)[(long long)b*P + p];
      sl1 += smoothl1(br.x - tx) + smoothl1(br.y - ty)
           + smoothl1(br.z - tw) + smoothl1(br.w - th);
    }
    labels_out[(long long)b*P + p] = lab;
  }
  float v = sl1; int c = cnt;
  for (int off=32; off>0; off>>=1){
    v += __shfl_down(v, off);
    c += __shfl_down(c, off);
  }
  if (lane == 0){ s_rs[wave] = v; s_rc[wave] = c; }
  __syncthreads();
  if (tid == 0){
    sl1_sum[b] = s_rs[0]+s_rs[1]+s_rs[2]+s_rs[3];
    num_pos[b] = s_rc[0]+s_rc[1]+s_rc[2]+s_rc[3];
  }
}

// Kernel 2: log-softmax stats: bg_loss per prior, CE sum over positives
__global__ __launch_bounds__(TPB) void lse_kernel(
    const float* __restrict__ logits,   // (B*P, NCLS)
    const int*   __restrict__ labels,   // (B*P)
    float* __restrict__ bg,             // (B*P): bg_loss, 0.0 for positives
    float* __restrict__ ce_pos,         // (B) atomic accumulate
    int P, long long nrows)
{
  __shared__ float s[ROWS*NCLS];
  const long long base = (long long)blockIdx.x * (ROWS*NCLS);
  const long long tot4 = (nrows * NCLS) >> 2;
  const long long base4 = base >> 2;
  const float4* gsrc = (const float4*)(logits + base);
  float4* sdst = (float4*)s;
  const int nf4 = (ROWS*NCLS)/4;   // 2592, exact (128*81*4B is 16B-multiple)
  for (int j = threadIdx.x; j < nf4; j += TPB){
    if (base4 + j < tot4) sdst[j] = gsrc[j];
  }
  __syncthreads();

  const int tid = threadIdx.x;
  const int rl = tid >> 1, half = tid & 1;
  const long long row = (long long)blockIdx.x * ROWS + rl;
  if (row < nrows){
    const float* x = s + rl*NCLS;
    const int c0 = half ? 41 : 0;
    const int c1 = half ? NCLS : 41;
    float m = -FLT_MAX;
    for (int c=c0; c<c1; ++c) m = fmaxf(m, x[c]);
    m = fmaxf(m, __shfl_xor(m, 1));
    float ssum = 0.0f;
    for (int c=c0; c<c1; ++c) ssum += expf(x[c]-m);
    ssum += __shfl_xor(ssum, 1);
    const float lse = m + logf(ssum);
    const int lab = labels[row];
    float xl = (lab >= c0 && lab < c1) ? x[lab] : 0.0f;
    xl += __shfl_xor(xl, 1);
    if (half == 0){
      if (lab > 0){
        const int b = (int)(row / P);
        atomicAdd(&ce_pos[b], lse - xl);
        bg[row] = 0.0f;
      } else {
        bg[row] = lse - xl;   // lab==0 -> xl = x[0]
      }
    }
  }
}

// Kernel 3: per-batch sum of top-(3*num_pos) bg values via 8-bit radix select.
// bg >= 0 so the raw float bit pattern is order-isomorphic to the value.
__global__ __launch_bounds__(TPB) void topk_kernel(
    const float* __restrict__ bg,
    const int*   __restrict__ num_pos,
    float* __restrict__ topk_sum,
    int P)
{
  const int b = blockIdx.x;
  const float* v = bg + (long long)b * P;
  __shared__ unsigned cnt[256];
  __shared__ float bsum[256];
  __shared__ unsigned s_prefix;
  __shared__ int s_krem;
  __shared__ float s_total;
  const int tid = threadIdx.x;
  if (tid == 0){
    int k = 3*num_pos[b];
    s_krem = k < P ? k : P-1;   // invariant: k < #elements
    s_total = 0.0f; s_prefix = 0u;
  }
  __syncthreads();
  for (int level=0; level<4; ++level){
    const int shift = 24 - 8*level;
    cnt[tid] = 0u; bsum[tid] = 0.0f;
    __syncthreads();
    const unsigned pref = s_prefix;
    for (int p = tid; p < P; p += TPB){
      const float f = v[p];
      const unsigned key = __float_as_uint(f);
      const bool ok = (level == 0) || ((key >> (shift+8)) == pref);
      if (ok){
        const unsigned bin = (key >> shift) & 255u;
        atomicAdd(&cnt[bin], 1u);
        atomicAdd(&bsum[bin], f);
      }
    }
    __syncthreads();
    if (tid == 0){
      const int k = s_krem;
      unsigned acc = 0; float sa = 0.0f; int chosen = 0;
      for (int bin=255; bin>=0; --bin){
        if (acc + cnt[bin] > (unsigned)k){ chosen = bin; break; }
        acc += cnt[bin]; sa += bsum[bin];
      }
      s_total += sa;
      s_krem = k - (int)acc;
      s_prefix = (pref << 8) | (unsigned)chosen;
    }
    __syncthreads();
  }
  if (tid == 0){
    topk_sum[b] = s_total + (float)s_krem * __uint_as_float(s_prefix);
  }
}

// Kernel 4: final reduce over B batches
__global__ __launch_bounds__(64) void final_kernel(
    const float* __restrict__ sl1_sum,
    const int*   __restrict__ num_pos,
    const float* __restrict__ ce_pos,
    const float* __restrict__ topk,
    float* __restrict__ out, int B)
{
  const int tid = threadIdx.x;
  float a = 0.0f, c = 0.0f, n = 0.0f;
  if (tid < B){
    a = sl1_sum[tid];
    c = ce_pos[tid] + topk[tid];
    n = (float)num_pos[tid];
  }
  for (int off=32; off>0; off>>=1){
    a += __shfl_down(a, off);
    c += __shfl_down(c, off);
    n += __shfl_down(n, off);
  }
  if (tid == 0){
    out[0] = a / n;   // loss_box_reg / num_pos
    out[1] = c / n;   // loss_classifier / num_pos
  }
}

extern "C" void kernel_launch(void* const* d_in, const int* in_sizes, int n_in,
                              void* d_out, int out_size, void* d_ws, size_t ws_size,
                              hipStream_t stream) {
  const float* priors = (const float*)d_in[0];
  const float* logits = (const float*)d_in[1];
  const float* boxreg = (const float*)d_in[2];
  const float* gtb    = (const float*)d_in[3];
  const int*   gtl    = (const int*)d_in[4];
  const int P = in_sizes[0] / 4;          // 8732
  const int B = in_sizes[4] / GT;         // 64
  const long long BP = (long long)B * P;

  char* ws = (char*)d_ws;
  int*   labels  = (int*)ws;                       // BP int
  float* bg      = (float*)(ws + BP*4);            // BP float
  float* sl1_s   = (float*)(ws + BP*8);            // B float
  int*   npos    = (int*)  (ws + BP*8 + (long long)B*4);
  float* ce_pos  = (float*)(ws + BP*8 + (long long)B*8);
  float* topk    = (float*)(ws + BP*8 + (long long)B*12);

  assign_kernel<<<B, TPB, 0, stream>>>(priors, gtb, gtl, boxreg,
                                       labels, sl1_s, npos, ce_pos, P);
  const int nblocks = (int)((BP + ROWS - 1) / ROWS);   // 4366 (exact)
  lse_kernel<<<nblocks, TPB, 0, stream>>>(logits, labels, bg, ce_pos, P, BP);
  topk_kernel<<<B, TPB, 0, stream>>>(bg, npos, topk, P);
  final_kernel<<<1, 64, 0, stream>>>(sl1_s, npos, ce_pos, topk, (float*)d_out, B);
}

// Round 2
// 447.848 us; speedup vs baseline: 1.1472x; 1.1472x over previous
//
#include <hip/hip_runtime.h>
#include <hip/hip_bf16.h>
#include <cfloat>

#define GT 16
#define NCLS 81
#define ROWS 64          // rows per lse block; 4 threads/row
#define TPB 256
#define MAXP 8732

__device__ __forceinline__ float smoothl1(float d){
  float a = fabsf(d);
  return a < 1.0f ? 0.5f*a*a : a - 0.5f;
}

// Kernel 1: per-batch GT<->prior assignment + box loss + labels
__global__ __launch_bounds__(TPB) void assign_kernel(
    const float* __restrict__ priors,     // (P,4) xywh
    const float* __restrict__ gt_boxes,   // (B,GT,4) xyxy
    const int*  __restrict__ gt_labels,   // (B,GT)
    const float* __restrict__ box_reg,    // (B,P,4)
    int*   __restrict__ labels_out,       // (B,P)
    float* __restrict__ sl1_sum,          // (B)
    int*   __restrict__ num_pos,          // (B)
    float* __restrict__ ce_pos,           // (B) zero-init here
    int P)
{
  const int b = blockIdx.x;
  const int tid = threadIdx.x;
  const int wave = tid >> 6, lane = tid & 63;

  __shared__ float s_mv[MAXP];
  __shared__ unsigned char s_match[MAXP];
  __shared__ float s_gx0[GT], s_gy0[GT], s_gx1[GT], s_gy1[GT], s_garea[GT];
  __shared__ int s_glab[GT];
  __shared__ float s_redv[4*GT];
  __shared__ int   s_redi[4*GT];
  __shared__ int   s_bp[GT];
  __shared__ float s_rs[4];
  __shared__ int   s_rc[4];

  if (tid == 0) ce_pos[b] = 0.0f;
  if (tid < GT){
    const float4 gb = ((const float4*)gt_boxes)[b*GT + tid];
    s_gx0[tid]=gb.x; s_gy0[tid]=gb.y; s_gx1[tid]=gb.z; s_gy1[tid]=gb.w;
    s_garea[tid] = (gb.z-gb.x)*(gb.w-gb.y);
    s_glab[tid] = gt_labels[b*GT + tid];
  }
  __syncthreads();

  float bestv[GT]; int besti[GT];
  #pragma unroll
  for (int g=0; g<GT; ++g){ bestv[g] = -1.0f; besti[g] = 0x7fffffff; }

  for (int p = tid; p < P; p += TPB){
    const float4 pr = ((const float4*)priors)[p];  // xywh
    const float px0 = pr.x - pr.z*0.5f, py0 = pr.y - pr.w*0.5f;
    const float px1 = pr.x + pr.z*0.5f, py1 = pr.y + pr.w*0.5f;
    const float parea = (px1-px0)*(py1-py0);
    float mv = -1.0f; int mi = 0;
    #pragma unroll
    for (int g=0; g<GT; ++g){
      const float ltx = fmaxf(s_gx0[g], px0), lty = fmaxf(s_gy0[g], py0);
      const float rbx = fminf(s_gx1[g], px1), rby = fminf(s_gy1[g], py1);
      const float w = fmaxf(rbx-ltx, 0.0f), h = fmaxf(rby-lty, 0.0f);
      const float inter = w*h;
      const float iou = inter / (s_garea[g] + parea - inter);
      if (iou > mv){ mv = iou; mi = g; }            // first-max over g
      if (iou > bestv[g]){ bestv[g] = iou; besti[g] = p; } // first-max over p (ascending)
    }
    s_mv[p] = mv;
    s_match[p] = (unsigned char)mi;
  }

  // reduce per-g (val, min idx on tie) across block
  #pragma unroll
  for (int g=0; g<GT; ++g){
    float v = bestv[g]; int i = besti[g];
    for (int off=32; off>0; off>>=1){
      float ov = __shfl_down(v, off);
      int   oi = __shfl_down(i, off);
      if (ov > v || (ov == v && oi < i)){ v = ov; i = oi; }
    }
    if (lane == 0){ s_redv[wave*GT+g] = v; s_redi[wave*GT+g] = i; }
  }
  __syncthreads();
  if (tid < GT){
    float v = s_redv[tid]; int i = s_redi[tid];
    for (int w=1; w<4; ++w){
      float ov = s_redv[w*GT+tid]; int oi = s_redi[w*GT+tid];
      if (ov > v || (ov == v && oi < i)){ v = ov; i = oi; }
    }
    s_bp[tid] = i;
  }
  __syncthreads();
  if (tid == 0){
    for (int g=0; g<GT; ++g){       // sequential: last g wins on duplicates
      int bp = s_bp[g];
      s_mv[bp] = 2.0f;
      s_match[bp] = (unsigned char)g;
    }
  }
  __syncthreads();

  // phase 2: labels + encode + smooth-L1 over positives
  float sl1 = 0.0f; int cnt = 0;
  for (int p = tid; p < P; p += TPB){
    const float mv = s_mv[p];
    const int g = s_match[p];
    int lab = 0;
    if (mv >= 0.5f){
      lab = s_glab[g];
      cnt++;
      const float4 pr = ((const float4*)priors)[p];
      const float bx0 = s_gx0[g], by0 = s_gy0[g], bx1 = s_gx1[g], by1 = s_gy1[g];
      const float ctrx = (bx0+bx1)*0.5f, ctry = (by0+by1)*0.5f;
      const float wx = bx1-bx0, wy = by1-by0;
      const float tx = (ctrx - pr.x) / (0.1f*pr.z);
      const float ty = (ctry - pr.y) / (0.1f*pr.w);
      const float tw = logf(wx/pr.z) / 0.2f;
      const float th = logf(wy/pr.w) / 0.2f;
      const float4 br = ((const float4*)box_reg)[(long long)b*P + p];
      sl1 += smoothl1(br.x - tx) + smoothl1(br.y - ty)
           + smoothl1(br.z - tw) + smoothl1(br.w - th);
    }
    labels_out[(long long)b*P + p] = lab;
  }
  float v = sl1; int c = cnt;
  for (int off=32; off>0; off>>=1){
    v += __shfl_down(v, off);
    c += __shfl_down(c, off);
  }
  if (lane == 0){ s_rs[wave] = v; s_rc[wave] = c; }
  __syncthreads();
  if (tid == 0){
    sl1_sum[b] = s_rs[0]+s_rs[1]+s_rs[2]+s_rs[3];
    num_pos[b] = s_rc[0]+s_rc[1]+s_rc[2]+s_rc[3];
  }
}

// Kernel 2: log-softmax stats: bg_loss per prior, CE sum over positives.
// 64 rows/block, 4 threads/row (~20 classes each). Exact-fit: B*P % 64 == 0,
// block bytes = 64*81*4 = 20736 (16B multiple) -> no bounds checks.
__global__ __launch_bounds__(TPB) void lse_kernel(
    const float* __restrict__ logits,   // (B*P, NCLS)
    const int*   __restrict__ labels,   // (B*P)
    float* __restrict__ bg,             // (B*P): bg_loss, 0.0 for positives
    float* __restrict__ ce_pos,         // (B) atomic accumulate
    int P)
{
  __shared__ float s[ROWS*NCLS];
  const long long base4 = (long long)blockIdx.x * (ROWS*NCLS/4);
  const float4* gsrc = (const float4*)logits + base4;
  float4* sdst = (float4*)s;
  #pragma unroll
  for (int j = 0; j < ROWS*NCLS/4/TPB + 1; ++j){   // 1296/256 -> 6 iters, last partial
    const int idx = threadIdx.x + j*TPB;
    if (idx < ROWS*NCLS/4) sdst[idx] = gsrc[idx];
  }
  __syncthreads();

  const int tid = threadIdx.x;
  const int rl = tid >> 2, q = tid & 3;
  const long long row = (long long)blockIdx.x * ROWS + rl;
  const float* x = s + rl*NCLS;
  const int c0 = q ? (1 + 20*q) : 0;       // [0,21) [21,41) [41,61) [61,81)
  const int c1 = 21 + 20*q;
  float m = -FLT_MAX;
  for (int c=c0; c<c1; ++c) m = fmaxf(m, x[c]);
  m = fmaxf(m, __shfl_xor(m, 1));
  m = fmaxf(m, __shfl_xor(m, 2));
  float ssum = 0.0f;
  for (int c=c0; c<c1; ++c) ssum += expf(x[c]-m);
  ssum += __shfl_xor(ssum, 1);
  ssum += __shfl_xor(ssum, 2);
  const float lse = m + logf(ssum);
  const int lab = labels[row];
  float xl = (lab >= c0 && lab < c1) ? x[lab] : 0.0f;
  xl += __shfl_xor(xl, 1);
  xl += __shfl_xor(xl, 2);
  if (q == 0){
    if (lab > 0){
      const int b = (int)(row / P);
      atomicAdd(&ce_pos[b], lse - xl);
      bg[row] = 0.0f;
    } else {
      bg[row] = lse - xl;   // lab==0 -> xl = x[0]
    }
  }
}

// Kernel 3: per-batch sum of top-(3*num_pos) bg values via 8-bit radix select.
// bg >= 0 so raw float bits are order-isomorphic to value. Data staged in LDS,
// per-wave replicated histograms, block-parallel suffix scan for bin choice.
__global__ __launch_bounds__(TPB) void topk_kernel(
    const float* __restrict__ bg,
    const int*   __restrict__ num_pos,
    float* __restrict__ topk_sum,
    int P)
{
  const int b = blockIdx.x;
  const int tid = threadIdx.x;
  const int wave = tid >> 6, lane = tid & 63;
  __shared__ float sv[MAXP];             // 35 KB staged values
  __shared__ unsigned cnt4[4][256];
  __shared__ float    bsum4[4][256];
  __shared__ unsigned s_wc[4];
  __shared__ float    s_wf[4];
  __shared__ unsigned s_prefix;
  __shared__ int s_krem, s_chosen, s_newk;
  __shared__ float s_total, s_addf;

  // stage: P = 8732 = 2183 float4 exactly
  {
    const float4* src = (const float4*)(bg + (long long)b * P);
    float4* dst = (float4*)sv;
    for (int j = tid; j < P/4; j += TPB) dst[j] = src[j];
  }
  if (tid == 0){
    int k = 3*num_pos[b];
    s_krem = k < P ? k : P-1;
    s_total = 0.0f; s_prefix = 0u;
  }
  __syncthreads();

  for (int level=0; level<4; ++level){
    const int shift = 24 - 8*level;
    for (int i = tid; i < 1024; i += TPB){
      ((unsigned*)cnt4)[i] = 0u; ((float*)bsum4)[i] = 0.0f;
    }
    __syncthreads();
    const unsigned pref = s_prefix;
    const int k = s_krem;
    for (int p = tid; p < P; p += TPB){
      const float f = sv[p];
      const unsigned key = __float_as_uint(f);
      const bool ok = (level == 0) || ((key >> (shift+8)) == pref);
      if (ok){
        const unsigned bin = (key >> shift) & 255u;
        atomicAdd(&cnt4[wave][bin], 1u);
        atomicAdd(&bsum4[wave][bin], f);
      }
    }
    __syncthreads();
    // suffix scan over bins (descending): thread t owns bin = 255 - t
    const int rb = 255 - tid;
    unsigned c = cnt4[0][rb] + cnt4[1][rb] + cnt4[2][rb] + cnt4[3][rb];
    float fs = bsum4[0][rb] + bsum4[1][rb] + bsum4[2][rb] + bsum4[3][rb];
    unsigned cv = c; float fv = fs;
    #pragma unroll
    for (int off=1; off<64; off<<=1){
      unsigned oc = __shfl_up(cv, off);
      float    of = __shfl_up(fv, off);
      if (lane >= off){ cv += oc; fv += of; }
    }
    if (lane == 63){ s_wc[wave] = cv; s_wf[wave] = fv; }
    __syncthreads();
    unsigned addc = 0; float addf = 0.0f;
    for (int w=0; w<4; ++w) if (w < wave){ addc += s_wc[w]; addf += s_wf[w]; }
    const unsigned S  = cv - c + addc;   // count in bins > rb (matching prefix)
    const float    Sf = fv - fs + addf;  // sum   in bins > rb
    if ((int)S <= k && k < (int)(S + c)){
      s_chosen = rb; s_newk = k - (int)S; s_addf = Sf;   // exactly one thread
    }
    __syncthreads();
    if (tid == 0){
      s_total += s_addf;
      s_krem = s_newk;
      s_prefix = (pref << 8) | (unsigned)s_chosen;
    }
    __syncthreads();
  }
  if (tid == 0){
    topk_sum[b] = s_total + (float)s_krem * __uint_as_float(s_prefix);
  }
}

// Kernel 4: final reduce over B batches
__global__ __launch_bounds__(64) void final_kernel(
    const float* __restrict__ sl1_sum,
    const int*   __restrict__ num_pos,
    const float* __restrict__ ce_pos,
    const float* __restrict__ topk,
    float* __restrict__ out, int B)
{
  const int tid = threadIdx.x;
  float a = 0.0f, c = 0.0f, n = 0.0f;
  if (tid < B){
    a = sl1_sum[tid];
    c = ce_pos[tid] + topk[tid];
    n = (float)num_pos[tid];
  }
  for (int off=32; off>0; off>>=1){
    a += __shfl_down(a, off);
    c += __shfl_down(c, off);
    n += __shfl_down(n, off);
  }
  if (tid == 0){
    out[0] = a / n;   // loss_box_reg / num_pos
    out[1] = c / n;   // loss_classifier / num_pos
  }
}

extern "C" void kernel_launch(void* const* d_in, const int* in_sizes, int n_in,
                              void* d_out, int out_size, void* d_ws, size_t ws_size,
                              hipStream_t stream) {
  const float* priors = (const float*)d_in[0];
  const float* logits = (const float*)d_in[1];
  const float* boxreg = (const float*)d_in[2];
  const float* gtb    = (const float*)d_in[3];
  const int*   gtl    = (const int*)d_in[4];
  const int P = in_sizes[0] / 4;          // 8732
  const int B = in_sizes[4] / GT;         // 64
  const long long BP = (long long)B * P;

  char* ws = (char*)d_ws;
  int*   labels  = (int*)ws;                       // BP int
  float* bg      = (float*)(ws + BP*4);            // BP float
  float* sl1_s   = (float*)(ws + BP*8);            // B float
  int*   npos    = (int*)  (ws + BP*8 + (long long)B*4);
  float* ce_pos  = (float*)(ws + BP*8 + (long long)B*8);
  float* topk    = (float*)(ws + BP*8 + (long long)B*12);

  assign_kernel<<<B, TPB, 0, stream>>>(priors, gtb, gtl, boxreg,
                                       labels, sl1_s, npos, ce_pos, P);
  const int nblocks = (int)(BP / ROWS);   // 8732 exact
  lse_kernel<<<nblocks, TPB, 0, stream>>>(logits, labels, bg, ce_pos, P);
  topk_kernel<<<B, TPB, 0, stream>>>(bg, npos, topk, P);
  final_kernel<<<1, 64, 0, stream>>>(sl1_s, npos, ce_pos, topk, (float*)d_out, B);
}